// Round 8
// baseline (240.640 us; speedup 1.0000x reference)
//
#include <hip/hip_runtime.h>

#define D 64
#define TILE 1024
#define RB 8               // dst ranges == XCD count
#define EPB 2048           // edges per chunk in hist/fill
#define EPT 8              // edges per thread (256 thr * 8 = 2048)

__device__ __forceinline__ float rlane(float v, int l) {
    return __int_as_float(__builtin_amdgcn_readlane(__float_as_int(v), l));
}

// ---------------------------------------------------------------------------
// Phase 1a: deg[dst]++ — range-partitioned (block residue r handles dst range
// r) with ballot-compaction: matching dsts are compacted into LDS so the
// atomic phase runs with full 64-lane waves instead of ~1/8 masked lanes.
// ---------------------------------------------------------------------------
__global__ __launch_bounds__(256) void hist_kernel(
    const int* __restrict__ edge_dst, int* __restrict__ deg,
    int n_edges, int n_nodes)
{
    __shared__ int s_cnt;
    __shared__ int s_d[EPB];
    int r = blockIdx.x & (RB - 1);
    int chunk = blockIdx.x >> 3;
    int lo = (int)((long long)r * n_nodes / RB);
    int hi = (int)((long long)(r + 1) * n_nodes / RB);
    if (threadIdx.x == 0) s_cnt = 0;
    __syncthreads();

    int base = chunk * EPB + threadIdx.x * EPT;
    int d[EPT];
    if (base + EPT - 1 < n_edges) {
        int4 v0 = *(const int4*)(edge_dst + base);
        int4 v1 = *(const int4*)(edge_dst + base + 4);
        d[0]=v0.x; d[1]=v0.y; d[2]=v0.z; d[3]=v0.w;
        d[4]=v1.x; d[5]=v1.y; d[6]=v1.z; d[7]=v1.w;
    } else {
        #pragma unroll
        for (int k = 0; k < EPT; ++k)
            d[k] = (base + k < n_edges) ? edge_dst[base + k] : -1;
    }

    int lane = threadIdx.x & 63;
    unsigned long long lt = (lane == 63) ? ~0ull >> 1
                                         : ((1ull << (lane + 1)) - 1) >> 1;
    #pragma unroll
    for (int k = 0; k < EPT; ++k) {
        bool m = (d[k] >= lo && d[k] < hi);
        unsigned long long bal = __ballot(m);
        int cw = __popcll(bal);
        if (cw) {
            int bs = 0;
            if (lane == 0) bs = atomicAdd(&s_cnt, cw);
            bs = __builtin_amdgcn_readfirstlane(bs);
            if (m) s_d[bs + __popcll(bal & lt)] = d[k];
        }
    }
    __syncthreads();
    int c = s_cnt;
    for (int i = threadIdx.x; i < c; i += 256) atomicAdd(&deg[s_d[i]], 1);
}

// ---------------------------------------------------------------------------
// Phase 1b-i: per-tile (1024 elems) sums. int4 loads, shfl reduce.
// ---------------------------------------------------------------------------
__global__ __launch_bounds__(256) void tile_sum_kernel(
    const int* __restrict__ deg, int* __restrict__ partial, int n)
{
    int t = threadIdx.x;
    int base = blockIdx.x * TILE + t * 4;
    int s = 0;
    if (base + 3 < n) {
        int4 v = *(const int4*)(deg + base);
        s = v.x + v.y + v.z + v.w;
    } else {
        for (int k = 0; k < 4; ++k) if (base + k < n) s += deg[base + k];
    }
    #pragma unroll
    for (int off = 1; off < 64; off <<= 1) s += __shfl_xor(s, off, 64);
    __shared__ int wsum[4];
    int lane = t & 63, wv = t >> 6;
    if (lane == 0) wsum[wv] = s;
    __syncthreads();
    if (t == 0) partial[blockIdx.x] = wsum[0] + wsum[1] + wsum[2] + wsum[3];
}

// ---------------------------------------------------------------------------
// Phase 1b-ii: exclusive scan of tile partials (1 block, 64 lanes).
// ---------------------------------------------------------------------------
__global__ __launch_bounds__(64) void scan_partial_kernel(
    const int* __restrict__ partial, int* __restrict__ ppref, int nb,
    int* __restrict__ offsets, int n, int n_edges)
{
    int lane = threadIdx.x;
    int carry = 0;
    for (int base = 0; base < nb; base += 64) {
        int idx = base + lane;
        int v = (idx < nb) ? partial[idx] : 0;
        int inc = v;
        #pragma unroll
        for (int off = 1; off < 64; off <<= 1) {
            int u = __shfl_up(inc, off, 64);
            if (lane >= off) inc += u;
        }
        if (idx < nb) ppref[idx] = carry + inc - v;
        carry += __shfl(inc, 63, 64);
    }
    if (lane == 0) offsets[n] = n_edges;
}

// ---------------------------------------------------------------------------
// Phase 1b-iii: per-tile scan -> offsets + cursor.
// ---------------------------------------------------------------------------
__global__ __launch_bounds__(256) void scan_tile_kernel(
    const int* __restrict__ deg, const int* __restrict__ ppref,
    int* __restrict__ offsets, int* __restrict__ cursor, int n)
{
    int t = threadIdx.x;
    int base = blockIdx.x * TILE + t * 4;
    int e0 = 0, e1 = 0, e2 = 0, e3 = 0;
    if (base + 3 < n) {
        int4 v = *(const int4*)(deg + base);
        e0 = v.x; e1 = v.y; e2 = v.z; e3 = v.w;
    } else {
        if (base + 0 < n) e0 = deg[base + 0];
        if (base + 1 < n) e1 = deg[base + 1];
        if (base + 2 < n) e2 = deg[base + 2];
        if (base + 3 < n) e3 = deg[base + 3];
    }
    int s = e0 + e1 + e2 + e3;
    int inc = s;
    int lane = t & 63, wv = t >> 6;
    #pragma unroll
    for (int off = 1; off < 64; off <<= 1) {
        int u = __shfl_up(inc, off, 64);
        if (lane >= off) inc += u;
    }
    __shared__ int wsum[4];
    if (lane == 63) wsum[wv] = inc;
    __syncthreads();
    int wpre = 0;
    for (int wq = 0; wq < wv; ++wq) wpre += wsum[wq];
    int excl = ppref[blockIdx.x] + wpre + inc - s;
    int o0 = excl, o1 = o0 + e0, o2 = o1 + e1, o3 = o2 + e2;
    if (base + 0 < n) { offsets[base + 0] = o0; cursor[base + 0] = o0; }
    if (base + 1 < n) { offsets[base + 1] = o1; cursor[base + 1] = o1; }
    if (base + 2 < n) { offsets[base + 2] = o2; cursor[base + 2] = o2; }
    if (base + 3 < n) { offsets[base + 3] = o3; cursor[base + 3] = o3; }
}

// ---------------------------------------------------------------------------
// Phase 1c: CSR fill, range-partitioned + ballot-compaction.
// ---------------------------------------------------------------------------
__global__ __launch_bounds__(256) void fill_kernel(
    const int* __restrict__ edge_src, const int* __restrict__ edge_dst,
    const float* __restrict__ edge_weight,
    int* __restrict__ cursor, int2* __restrict__ csr_sw,
    int n_edges, int n_nodes)
{
    __shared__ int s_cnt;
    __shared__ int s_d[EPB];
    __shared__ int s_e[EPB];
    int r = blockIdx.x & (RB - 1);
    int chunk = blockIdx.x >> 3;
    int lo = (int)((long long)r * n_nodes / RB);
    int hi = (int)((long long)(r + 1) * n_nodes / RB);
    if (threadIdx.x == 0) s_cnt = 0;
    __syncthreads();

    int base = chunk * EPB + threadIdx.x * EPT;
    int d[EPT];
    if (base + EPT - 1 < n_edges) {
        int4 v0 = *(const int4*)(edge_dst + base);
        int4 v1 = *(const int4*)(edge_dst + base + 4);
        d[0]=v0.x; d[1]=v0.y; d[2]=v0.z; d[3]=v0.w;
        d[4]=v1.x; d[5]=v1.y; d[6]=v1.z; d[7]=v1.w;
    } else {
        #pragma unroll
        for (int k = 0; k < EPT; ++k)
            d[k] = (base + k < n_edges) ? edge_dst[base + k] : -1;
    }

    int lane = threadIdx.x & 63;
    unsigned long long lt = (lane == 63) ? ~0ull >> 1
                                         : ((1ull << (lane + 1)) - 1) >> 1;
    #pragma unroll
    for (int k = 0; k < EPT; ++k) {
        bool m = (d[k] >= lo && d[k] < hi);
        unsigned long long bal = __ballot(m);
        int cw = __popcll(bal);
        if (cw) {
            int bs = 0;
            if (lane == 0) bs = atomicAdd(&s_cnt, cw);
            bs = __builtin_amdgcn_readfirstlane(bs);
            if (m) {
                int p = bs + __popcll(bal & lt);
                s_d[p] = d[k];
                s_e[p] = base + k;
            }
        }
    }
    __syncthreads();
    int c = s_cnt;
    for (int i = threadIdx.x; i < c; i += 256) {
        int dk = s_d[i];
        int e  = s_e[i];
        int pos = atomicAdd(&cursor[dk], 1);
        csr_sw[pos] = make_int2(edge_src[e], __float_as_int(edge_weight[e]));
    }
}

// ---------------------------------------------------------------------------
// Phase 2: wave-per-node gather, 8-deep ILP. csr reads wave-uniform (s_load);
// feature rows 256B-coalesced.
// ---------------------------------------------------------------------------
__global__ __launch_bounds__(256) void gather_kernel(
    const float* __restrict__ features, const int2* __restrict__ csr_sw,
    const int* __restrict__ offsets, float* __restrict__ neighbor, int n_nodes)
{
    int lane = threadIdx.x & 63;
    int gw = (blockIdx.x * 256 + threadIdx.x) >> 6;
    int nw = (gridDim.x * 256) >> 6;
    for (int i = gw; i < n_nodes; i += nw) {
        int beg = __builtin_amdgcn_readfirstlane(offsets[i]);
        int end = __builtin_amdgcn_readfirstlane(offsets[i + 1]);
        float acc = 0.f;
        int j = beg;
        for (; j + 7 < end; j += 8) {
            int2 p[8];
            float a[8];
            #pragma unroll
            for (int q = 0; q < 8; ++q) p[q] = csr_sw[j + q];
            #pragma unroll
            for (int q = 0; q < 8; ++q)
                a[q] = features[(size_t)p[q].x * D + lane];
            #pragma unroll
            for (int q = 0; q < 8; ++q)
                acc = fmaf(__int_as_float(p[q].y), a[q], acc);
        }
        for (; j < end; ++j) {
            int2 p = csr_sw[j];
            acc = fmaf(__int_as_float(p.y), features[(size_t)p.x * D + lane], acc);
        }
        neighbor[(size_t)i * D + lane] = acc;
    }
}

// ---------------------------------------------------------------------------
// Phase 3: out = normalize([features | neighbor] @ W^T + b)
// Lane o holds W row o (128 floats) PINNED in VGPRs:
//  - __launch_bounds__(256, 1) lifts the allocator's wave-target register cap
//  - keep-alive asm makes each element an opaque VGPR value the compiler
//    cannot rematerialize from memory (round-7 lesson: VGPR=80 meant W was
//    re-fetched from L2 every node-iter, ~1.6GB L2 traffic = the 49us).
// 4 independent fma chains; broadcast via v_readlane (VALU pipe, no DS).
// ---------------------------------------------------------------------------
__global__ __launch_bounds__(256, 1) void gemm_norm_kernel(
    const float* __restrict__ features, const float* __restrict__ neighbor,
    const float* __restrict__ W, const float* __restrict__ bias,
    float* __restrict__ out, int n_nodes)
{
    int lane = threadIdx.x & 63;
    float wr[128];
    const float4* Wv = (const float4*)(W + (size_t)lane * 128);
    #pragma unroll
    for (int q = 0; q < 32; ++q) {
        float4 v = Wv[q];
        wr[4 * q + 0] = v.x; wr[4 * q + 1] = v.y;
        wr[4 * q + 2] = v.z; wr[4 * q + 3] = v.w;
    }
    // pin W row in VGPRs — compiler cannot rematerialize past this point
    #pragma unroll
    for (int q = 0; q < 128; ++q)
        asm volatile("" : "+v"(wr[q]));
    float bl = bias[lane];

    int gw = (blockIdx.x * 256 + threadIdx.x) >> 6;
    int nw = (gridDim.x * 256) >> 6;
    for (int i = gw; i < n_nodes; i += nw) {
        float cf = features[(size_t)i * D + lane];
        float cn = neighbor[(size_t)i * D + lane];
        float a0 = bl, a1 = 0.f, a2 = 0.f, a3 = 0.f;
        #pragma unroll
        for (int k = 0; k < 32; ++k) {
            a0 = fmaf(rlane(cf, k),      wr[k],      a0);
            a1 = fmaf(rlane(cf, k + 32), wr[k + 32], a1);
            a2 = fmaf(rlane(cn, k),      wr[k + 64], a2);
            a3 = fmaf(rlane(cn, k + 32), wr[k + 96], a3);
        }
        float acc = (a0 + a1) + (a2 + a3);
        float s = acc * acc;
        #pragma unroll
        for (int m = 1; m < 64; m <<= 1) s += __shfl_xor(s, m, 64);
        out[(size_t)i * D + lane] = acc / fmaxf(sqrtf(s), 1e-12f);
    }
}

extern "C" void kernel_launch(void* const* d_in, const int* in_sizes, int n_in,
                              void* d_out, int out_size, void* d_ws, size_t ws_size,
                              hipStream_t stream) {
    const float* features    = (const float*)d_in[0];
    const int*   edge_src    = (const int*)d_in[1];
    const int*   edge_dst    = (const int*)d_in[2];
    const float* edge_weight = (const float*)d_in[3];
    const float* W           = (const float*)d_in[4];
    const float* b           = (const float*)d_in[5];
    float*       out         = (float*)d_out;

    int n = in_sizes[0] / D;
    int E = in_sizes[1];
    int nb = (n + TILE - 1) / TILE;
    int nchunks = (E + EPB - 1) / EPB;

    // workspace layout (256B-aligned slabs)
    char* ws = (char*)d_ws;
    auto al = [](size_t x) { return (x + 255) & ~(size_t)255; };
    size_t o = 0;
    int* deg      = (int*)(ws + o); o += al((size_t)n * 4);
    int* cursor   = (int*)(ws + o); o += al((size_t)n * 4);
    int* offsets  = (int*)(ws + o); o += al((size_t)(n + 1) * 4);
    int* partial  = (int*)(ws + o); o += al((size_t)nb * 4);
    int* ppref    = (int*)(ws + o); o += al((size_t)nb * 4);
    int2* csr_sw  = (int2*)(ws + o); o += al((size_t)E * 8);
    float* neighbor = (float*)(ws + o);

    hipMemsetAsync(deg, 0, (size_t)n * 4, stream);

    hist_kernel<<<nchunks * RB, 256, 0, stream>>>(edge_dst, deg, E, n);
    tile_sum_kernel<<<nb, 256, 0, stream>>>(deg, partial, n);
    scan_partial_kernel<<<1, 64, 0, stream>>>(partial, ppref, nb, offsets, n, E);
    scan_tile_kernel<<<nb, 256, 0, stream>>>(deg, ppref, offsets, cursor, n);
    fill_kernel<<<nchunks * RB, 256, 0, stream>>>(edge_src, edge_dst, edge_weight,
                                                  cursor, csr_sw, E, n);
    gather_kernel<<<2048, 256, 0, stream>>>(features, csr_sw, offsets,
                                            neighbor, n);
    gemm_norm_kernel<<<2048, 256, 0, stream>>>(features, neighbor, W, b, out, n);
}

// Round 9
// 230.033 us; speedup vs baseline: 1.0461x; 1.0461x over previous
//
#include <hip/hip_runtime.h>

#define D 64
#define TILE 1024
#define RB 8               // dst ranges == XCD count
#define EPB 2048           // edges per chunk in hist/fill
#define EPT 8              // edges per thread (256 thr * 8 = 2048)

__device__ __forceinline__ float rlane(float v, int l) {
    return __int_as_float(__builtin_amdgcn_readlane(__float_as_int(v), l));
}

// ---------------------------------------------------------------------------
// Phase 1a: deg[dst]++ — range-partitioned + ballot-compaction.
// ---------------------------------------------------------------------------
__global__ __launch_bounds__(256) void hist_kernel(
    const int* __restrict__ edge_dst, int* __restrict__ deg,
    int n_edges, int n_nodes)
{
    __shared__ int s_cnt;
    __shared__ int s_d[EPB];
    int r = blockIdx.x & (RB - 1);
    int chunk = blockIdx.x >> 3;
    int lo = (int)((long long)r * n_nodes / RB);
    int hi = (int)((long long)(r + 1) * n_nodes / RB);
    if (threadIdx.x == 0) s_cnt = 0;
    __syncthreads();

    int base = chunk * EPB + threadIdx.x * EPT;
    int d[EPT];
    if (base + EPT - 1 < n_edges) {
        int4 v0 = *(const int4*)(edge_dst + base);
        int4 v1 = *(const int4*)(edge_dst + base + 4);
        d[0]=v0.x; d[1]=v0.y; d[2]=v0.z; d[3]=v0.w;
        d[4]=v1.x; d[5]=v1.y; d[6]=v1.z; d[7]=v1.w;
    } else {
        #pragma unroll
        for (int k = 0; k < EPT; ++k)
            d[k] = (base + k < n_edges) ? edge_dst[base + k] : -1;
    }

    int lane = threadIdx.x & 63;
    unsigned long long lt = (lane == 63) ? ~0ull >> 1
                                         : ((1ull << (lane + 1)) - 1) >> 1;
    #pragma unroll
    for (int k = 0; k < EPT; ++k) {
        bool m = (d[k] >= lo && d[k] < hi);
        unsigned long long bal = __ballot(m);
        int cw = __popcll(bal);
        if (cw) {
            int bs = 0;
            if (lane == 0) bs = atomicAdd(&s_cnt, cw);
            bs = __builtin_amdgcn_readfirstlane(bs);
            if (m) s_d[bs + __popcll(bal & lt)] = d[k];
        }
    }
    __syncthreads();
    int c = s_cnt;
    for (int i = threadIdx.x; i < c; i += 256) atomicAdd(&deg[s_d[i]], 1);
}

// ---------------------------------------------------------------------------
// Phase 1b-i: per-tile (1024 elems) sums. int4 loads, shfl reduce.
// ---------------------------------------------------------------------------
__global__ __launch_bounds__(256) void tile_sum_kernel(
    const int* __restrict__ deg, int* __restrict__ partial, int n)
{
    int t = threadIdx.x;
    int base = blockIdx.x * TILE + t * 4;
    int s = 0;
    if (base + 3 < n) {
        int4 v = *(const int4*)(deg + base);
        s = v.x + v.y + v.z + v.w;
    } else {
        for (int k = 0; k < 4; ++k) if (base + k < n) s += deg[base + k];
    }
    #pragma unroll
    for (int off = 1; off < 64; off <<= 1) s += __shfl_xor(s, off, 64);
    __shared__ int wsum[4];
    int lane = t & 63, wv = t >> 6;
    if (lane == 0) wsum[wv] = s;
    __syncthreads();
    if (t == 0) partial[blockIdx.x] = wsum[0] + wsum[1] + wsum[2] + wsum[3];
}

// ---------------------------------------------------------------------------
// Phase 1b-ii: exclusive scan of tile partials (1 block, 64 lanes).
// ---------------------------------------------------------------------------
__global__ __launch_bounds__(64) void scan_partial_kernel(
    const int* __restrict__ partial, int* __restrict__ ppref, int nb,
    int* __restrict__ offsets, int n, int n_edges)
{
    int lane = threadIdx.x;
    int carry = 0;
    for (int base = 0; base < nb; base += 64) {
        int idx = base + lane;
        int v = (idx < nb) ? partial[idx] : 0;
        int inc = v;
        #pragma unroll
        for (int off = 1; off < 64; off <<= 1) {
            int u = __shfl_up(inc, off, 64);
            if (lane >= off) inc += u;
        }
        if (idx < nb) ppref[idx] = carry + inc - v;
        carry += __shfl(inc, 63, 64);
    }
    if (lane == 0) offsets[n] = n_edges;
}

// ---------------------------------------------------------------------------
// Phase 1b-iii: per-tile scan -> offsets + cursor.
// ---------------------------------------------------------------------------
__global__ __launch_bounds__(256) void scan_tile_kernel(
    const int* __restrict__ deg, const int* __restrict__ ppref,
    int* __restrict__ offsets, int* __restrict__ cursor, int n)
{
    int t = threadIdx.x;
    int base = blockIdx.x * TILE + t * 4;
    int e0 = 0, e1 = 0, e2 = 0, e3 = 0;
    if (base + 3 < n) {
        int4 v = *(const int4*)(deg + base);
        e0 = v.x; e1 = v.y; e2 = v.z; e3 = v.w;
    } else {
        if (base + 0 < n) e0 = deg[base + 0];
        if (base + 1 < n) e1 = deg[base + 1];
        if (base + 2 < n) e2 = deg[base + 2];
        if (base + 3 < n) e3 = deg[base + 3];
    }
    int s = e0 + e1 + e2 + e3;
    int inc = s;
    int lane = t & 63, wv = t >> 6;
    #pragma unroll
    for (int off = 1; off < 64; off <<= 1) {
        int u = __shfl_up(inc, off, 64);
        if (lane >= off) inc += u;
    }
    __shared__ int wsum[4];
    if (lane == 63) wsum[wv] = inc;
    __syncthreads();
    int wpre = 0;
    for (int wq = 0; wq < wv; ++wq) wpre += wsum[wq];
    int excl = ppref[blockIdx.x] + wpre + inc - s;
    int o0 = excl, o1 = o0 + e0, o2 = o1 + e1, o3 = o2 + e2;
    if (base + 0 < n) { offsets[base + 0] = o0; cursor[base + 0] = o0; }
    if (base + 1 < n) { offsets[base + 1] = o1; cursor[base + 1] = o1; }
    if (base + 2 < n) { offsets[base + 2] = o2; cursor[base + 2] = o2; }
    if (base + 3 < n) { offsets[base + 3] = o3; cursor[base + 3] = o3; }
}

// ---------------------------------------------------------------------------
// Phase 1c: CSR fill, range-partitioned + ballot-compaction.
// ---------------------------------------------------------------------------
__global__ __launch_bounds__(256) void fill_kernel(
    const int* __restrict__ edge_src, const int* __restrict__ edge_dst,
    const float* __restrict__ edge_weight,
    int* __restrict__ cursor, int2* __restrict__ csr_sw,
    int n_edges, int n_nodes)
{
    __shared__ int s_cnt;
    __shared__ int s_d[EPB];
    __shared__ int s_e[EPB];
    int r = blockIdx.x & (RB - 1);
    int chunk = blockIdx.x >> 3;
    int lo = (int)((long long)r * n_nodes / RB);
    int hi = (int)((long long)(r + 1) * n_nodes / RB);
    if (threadIdx.x == 0) s_cnt = 0;
    __syncthreads();

    int base = chunk * EPB + threadIdx.x * EPT;
    int d[EPT];
    if (base + EPT - 1 < n_edges) {
        int4 v0 = *(const int4*)(edge_dst + base);
        int4 v1 = *(const int4*)(edge_dst + base + 4);
        d[0]=v0.x; d[1]=v0.y; d[2]=v0.z; d[3]=v0.w;
        d[4]=v1.x; d[5]=v1.y; d[6]=v1.z; d[7]=v1.w;
    } else {
        #pragma unroll
        for (int k = 0; k < EPT; ++k)
            d[k] = (base + k < n_edges) ? edge_dst[base + k] : -1;
    }

    int lane = threadIdx.x & 63;
    unsigned long long lt = (lane == 63) ? ~0ull >> 1
                                         : ((1ull << (lane + 1)) - 1) >> 1;
    #pragma unroll
    for (int k = 0; k < EPT; ++k) {
        bool m = (d[k] >= lo && d[k] < hi);
        unsigned long long bal = __ballot(m);
        int cw = __popcll(bal);
        if (cw) {
            int bs = 0;
            if (lane == 0) bs = atomicAdd(&s_cnt, cw);
            bs = __builtin_amdgcn_readfirstlane(bs);
            if (m) {
                int p = bs + __popcll(bal & lt);
                s_d[p] = d[k];
                s_e[p] = base + k;
            }
        }
    }
    __syncthreads();
    int c = s_cnt;
    for (int i = threadIdx.x; i < c; i += 256) {
        int dk = s_d[i];
        int e  = s_e[i];
        int pos = atomicAdd(&cursor[dk], 1);
        csr_sw[pos] = make_int2(edge_src[e], __float_as_int(edge_weight[e]));
    }
}

// ---------------------------------------------------------------------------
// Phase 2: wave-per-node gather, 8-deep ILP. csr reads wave-uniform;
// feature rows 256B-coalesced.
// ---------------------------------------------------------------------------
__global__ __launch_bounds__(256) void gather_kernel(
    const float* __restrict__ features, const int2* __restrict__ csr_sw,
    const int* __restrict__ offsets, float* __restrict__ neighbor, int n_nodes)
{
    int lane = threadIdx.x & 63;
    int gw = (blockIdx.x * 256 + threadIdx.x) >> 6;
    int nw = (gridDim.x * 256) >> 6;
    for (int i = gw; i < n_nodes; i += nw) {
        int beg = __builtin_amdgcn_readfirstlane(offsets[i]);
        int end = __builtin_amdgcn_readfirstlane(offsets[i + 1]);
        float acc = 0.f;
        int j = beg;
        for (; j + 7 < end; j += 8) {
            int2 p[8];
            float a[8];
            #pragma unroll
            for (int q = 0; q < 8; ++q) p[q] = csr_sw[j + q];
            #pragma unroll
            for (int q = 0; q < 8; ++q)
                a[q] = features[(size_t)p[q].x * D + lane];
            #pragma unroll
            for (int q = 0; q < 8; ++q)
                acc = fmaf(__int_as_float(p[q].y), a[q], acc);
        }
        for (; j < end; ++j) {
            int2 p = csr_sw[j];
            acc = fmaf(__int_as_float(p.y), features[(size_t)p.x * D + lane], acc);
        }
        neighbor[(size_t)i * D + lane] = acc;
    }
}

// ---------------------------------------------------------------------------
// Phase 3: out = normalize([features | neighbor] @ W^T + b)
// Round-8 lesson: per-lane W-in-VGPR is unallocatable (compiler remat/spills;
// 1.6GB L2 re-read = the 49-59us). Instead REUSE W across nodes:
//  - W transposed in LDS as Wt4[k4][o] (float4): at step k4, lane o does ONE
//    conflict-free ds_read_b128, reused for T=8 nodes (32 fma per read).
//  - 8 nodes in flight per wave: cf[8]/cn[8]/acc[8] ~ 60 VGPR, no pin needed.
//  - readlane broadcast (VALU); k4 loop counter stays in SGPR.
// W traffic/node-iter drops 8x; kernel becomes VALU-bound (~11us floor).
// ---------------------------------------------------------------------------
__global__ __launch_bounds__(256) void gemm_norm_kernel(
    const float* __restrict__ features, const float* __restrict__ neighbor,
    const float* __restrict__ W, const float* __restrict__ bias,
    float* __restrict__ out, int n_nodes)
{
    __shared__ float4 Wt4[32][64];   // Wt4[k4][o] = W[o][4k4 .. 4k4+3], 32KB
    int tid = threadIdx.x;
    #pragma unroll
    for (int idx = tid; idx < 32 * 64; idx += 256) {
        int k4 = idx >> 6, o = idx & 63;
        Wt4[k4][o] = *(const float4*)(W + (size_t)o * 128 + k4 * 4);
    }
    __syncthreads();

    int lane = tid & 63;
    int wv = tid >> 6;
    float bl = bias[lane];

    int g = blockIdx.x * 4 + wv;       // this wave's group of 8 nodes
    int i0 = g * 8;
    if (i0 >= n_nodes) return;
    int cnt = min(8, n_nodes - i0);

    float cf[8], cn[8], acc[8];
    #pragma unroll
    for (int t = 0; t < 8; ++t) {
        int i = i0 + ((t < cnt) ? t : 0);   // clamp tail (not stored)
        cf[t] = features[(size_t)i * D + lane];
        cn[t] = neighbor[(size_t)i * D + lane];
        acc[t] = bl;
    }

    // k = 0..63 (features half)
    #pragma unroll 4
    for (int k4 = 0; k4 < 16; ++k4) {
        float4 w4 = Wt4[k4][lane];
        int kb = 4 * k4;
        #pragma unroll
        for (int t = 0; t < 8; ++t) {
            acc[t] = fmaf(rlane(cf[t], kb + 0), w4.x, acc[t]);
            acc[t] = fmaf(rlane(cf[t], kb + 1), w4.y, acc[t]);
            acc[t] = fmaf(rlane(cf[t], kb + 2), w4.z, acc[t]);
            acc[t] = fmaf(rlane(cf[t], kb + 3), w4.w, acc[t]);
        }
    }
    // k = 64..127 (neighbor half)
    #pragma unroll 4
    for (int k4 = 16; k4 < 32; ++k4) {
        float4 w4 = Wt4[k4][lane];
        int kb = 4 * k4 - 64;
        #pragma unroll
        for (int t = 0; t < 8; ++t) {
            acc[t] = fmaf(rlane(cn[t], kb + 0), w4.x, acc[t]);
            acc[t] = fmaf(rlane(cn[t], kb + 1), w4.y, acc[t]);
            acc[t] = fmaf(rlane(cn[t], kb + 2), w4.z, acc[t]);
            acc[t] = fmaf(rlane(cn[t], kb + 3), w4.w, acc[t]);
        }
    }

    #pragma unroll
    for (int t = 0; t < 8; ++t) {
        if (t < cnt) {
            float s = acc[t] * acc[t];
            #pragma unroll
            for (int m = 1; m < 64; m <<= 1) s += __shfl_xor(s, m, 64);
            out[(size_t)(i0 + t) * D + lane] = acc[t] / fmaxf(sqrtf(s), 1e-12f);
        }
    }
}

extern "C" void kernel_launch(void* const* d_in, const int* in_sizes, int n_in,
                              void* d_out, int out_size, void* d_ws, size_t ws_size,
                              hipStream_t stream) {
    const float* features    = (const float*)d_in[0];
    const int*   edge_src    = (const int*)d_in[1];
    const int*   edge_dst    = (const int*)d_in[2];
    const float* edge_weight = (const float*)d_in[3];
    const float* W           = (const float*)d_in[4];
    const float* b           = (const float*)d_in[5];
    float*       out         = (float*)d_out;

    int n = in_sizes[0] / D;
    int E = in_sizes[1];
    int nb = (n + TILE - 1) / TILE;
    int nchunks = (E + EPB - 1) / EPB;

    // workspace layout (256B-aligned slabs)
    char* ws = (char*)d_ws;
    auto al = [](size_t x) { return (x + 255) & ~(size_t)255; };
    size_t o = 0;
    int* deg      = (int*)(ws + o); o += al((size_t)n * 4);
    int* cursor   = (int*)(ws + o); o += al((size_t)n * 4);
    int* offsets  = (int*)(ws + o); o += al((size_t)(n + 1) * 4);
    int* partial  = (int*)(ws + o); o += al((size_t)nb * 4);
    int* ppref    = (int*)(ws + o); o += al((size_t)nb * 4);
    int2* csr_sw  = (int2*)(ws + o); o += al((size_t)E * 8);
    float* neighbor = (float*)(ws + o);

    hipMemsetAsync(deg, 0, (size_t)n * 4, stream);

    hist_kernel<<<nchunks * RB, 256, 0, stream>>>(edge_dst, deg, E, n);
    tile_sum_kernel<<<nb, 256, 0, stream>>>(deg, partial, n);
    scan_partial_kernel<<<1, 64, 0, stream>>>(partial, ppref, nb, offsets, n, E);
    scan_tile_kernel<<<nb, 256, 0, stream>>>(deg, ppref, offsets, cursor, n);
    fill_kernel<<<nchunks * RB, 256, 0, stream>>>(edge_src, edge_dst, edge_weight,
                                                  cursor, csr_sw, E, n);
    gather_kernel<<<2048, 256, 0, stream>>>(features, csr_sw, offsets,
                                            neighbor, n);
    int groups = (n + 7) / 8;
    gemm_norm_kernel<<<(groups + 3) / 4, 256, 0, stream>>>(features, neighbor,
                                                           W, b, out, n);
}

// Round 10
// 228.424 us; speedup vs baseline: 1.0535x; 1.0070x over previous
//
#include <hip/hip_runtime.h>

#define D 64
#define TILE 1024
#define RB 8               // dst ranges == XCD count
#define EPB 2048           // edges per chunk in hist/fill
#define EPT 8              // edges per thread (256 thr * 8 = 2048)

// ---------------------------------------------------------------------------
// Phase 1a: deg[dst]++ — range-partitioned + ballot-compaction.
// ---------------------------------------------------------------------------
__global__ __launch_bounds__(256) void hist_kernel(
    const int* __restrict__ edge_dst, int* __restrict__ deg,
    int n_edges, int n_nodes)
{
    __shared__ int s_cnt;
    __shared__ int s_d[EPB];
    int r = blockIdx.x & (RB - 1);
    int chunk = blockIdx.x >> 3;
    int lo = (int)((long long)r * n_nodes / RB);
    int hi = (int)((long long)(r + 1) * n_nodes / RB);
    if (threadIdx.x == 0) s_cnt = 0;
    __syncthreads();

    int base = chunk * EPB + threadIdx.x * EPT;
    int d[EPT];
    if (base + EPT - 1 < n_edges) {
        int4 v0 = *(const int4*)(edge_dst + base);
        int4 v1 = *(const int4*)(edge_dst + base + 4);
        d[0]=v0.x; d[1]=v0.y; d[2]=v0.z; d[3]=v0.w;
        d[4]=v1.x; d[5]=v1.y; d[6]=v1.z; d[7]=v1.w;
    } else {
        #pragma unroll
        for (int k = 0; k < EPT; ++k)
            d[k] = (base + k < n_edges) ? edge_dst[base + k] : -1;
    }

    int lane = threadIdx.x & 63;
    unsigned long long lt = (lane == 63) ? ~0ull >> 1
                                         : ((1ull << (lane + 1)) - 1) >> 1;
    #pragma unroll
    for (int k = 0; k < EPT; ++k) {
        bool m = (d[k] >= lo && d[k] < hi);
        unsigned long long bal = __ballot(m);
        int cw = __popcll(bal);
        if (cw) {
            int bs = 0;
            if (lane == 0) bs = atomicAdd(&s_cnt, cw);
            bs = __builtin_amdgcn_readfirstlane(bs);
            if (m) s_d[bs + __popcll(bal & lt)] = d[k];
        }
    }
    __syncthreads();
    int c = s_cnt;
    for (int i = threadIdx.x; i < c; i += 256) atomicAdd(&deg[s_d[i]], 1);
}

// ---------------------------------------------------------------------------
// Phase 1b-i: per-tile (1024 elems) sums. int4 loads, shfl reduce.
// ---------------------------------------------------------------------------
__global__ __launch_bounds__(256) void tile_sum_kernel(
    const int* __restrict__ deg, int* __restrict__ partial, int n)
{
    int t = threadIdx.x;
    int base = blockIdx.x * TILE + t * 4;
    int s = 0;
    if (base + 3 < n) {
        int4 v = *(const int4*)(deg + base);
        s = v.x + v.y + v.z + v.w;
    } else {
        for (int k = 0; k < 4; ++k) if (base + k < n) s += deg[base + k];
    }
    #pragma unroll
    for (int off = 1; off < 64; off <<= 1) s += __shfl_xor(s, off, 64);
    __shared__ int wsum[4];
    int lane = t & 63, wv = t >> 6;
    if (lane == 0) wsum[wv] = s;
    __syncthreads();
    if (t == 0) partial[blockIdx.x] = wsum[0] + wsum[1] + wsum[2] + wsum[3];
}

// ---------------------------------------------------------------------------
// Phase 1b-ii: exclusive scan of tile partials (1 block, 64 lanes).
// ---------------------------------------------------------------------------
__global__ __launch_bounds__(64) void scan_partial_kernel(
    const int* __restrict__ partial, int* __restrict__ ppref, int nb,
    int* __restrict__ offsets, int n, int n_edges)
{
    int lane = threadIdx.x;
    int carry = 0;
    for (int base = 0; base < nb; base += 64) {
        int idx = base + lane;
        int v = (idx < nb) ? partial[idx] : 0;
        int inc = v;
        #pragma unroll
        for (int off = 1; off < 64; off <<= 1) {
            int u = __shfl_up(inc, off, 64);
            if (lane >= off) inc += u;
        }
        if (idx < nb) ppref[idx] = carry + inc - v;
        carry += __shfl(inc, 63, 64);
    }
    if (lane == 0) offsets[n] = n_edges;
}

// ---------------------------------------------------------------------------
// Phase 1b-iii: per-tile scan -> offsets + cursor.
// ---------------------------------------------------------------------------
__global__ __launch_bounds__(256) void scan_tile_kernel(
    const int* __restrict__ deg, const int* __restrict__ ppref,
    int* __restrict__ offsets, int* __restrict__ cursor, int n)
{
    int t = threadIdx.x;
    int base = blockIdx.x * TILE + t * 4;
    int e0 = 0, e1 = 0, e2 = 0, e3 = 0;
    if (base + 3 < n) {
        int4 v = *(const int4*)(deg + base);
        e0 = v.x; e1 = v.y; e2 = v.z; e3 = v.w;
    } else {
        if (base + 0 < n) e0 = deg[base + 0];
        if (base + 1 < n) e1 = deg[base + 1];
        if (base + 2 < n) e2 = deg[base + 2];
        if (base + 3 < n) e3 = deg[base + 3];
    }
    int s = e0 + e1 + e2 + e3;
    int inc = s;
    int lane = t & 63, wv = t >> 6;
    #pragma unroll
    for (int off = 1; off < 64; off <<= 1) {
        int u = __shfl_up(inc, off, 64);
        if (lane >= off) inc += u;
    }
    __shared__ int wsum[4];
    if (lane == 63) wsum[wv] = inc;
    __syncthreads();
    int wpre = 0;
    for (int wq = 0; wq < wv; ++wq) wpre += wsum[wq];
    int excl = ppref[blockIdx.x] + wpre + inc - s;
    int o0 = excl, o1 = o0 + e0, o2 = o1 + e1, o3 = o2 + e2;
    if (base + 0 < n) { offsets[base + 0] = o0; cursor[base + 0] = o0; }
    if (base + 1 < n) { offsets[base + 1] = o1; cursor[base + 1] = o1; }
    if (base + 2 < n) { offsets[base + 2] = o2; cursor[base + 2] = o2; }
    if (base + 3 < n) { offsets[base + 3] = o3; cursor[base + 3] = o3; }
}

// ---------------------------------------------------------------------------
// Phase 1c: CSR fill, range-partitioned + ballot-compaction.
// ---------------------------------------------------------------------------
__global__ __launch_bounds__(256) void fill_kernel(
    const int* __restrict__ edge_src, const int* __restrict__ edge_dst,
    const float* __restrict__ edge_weight,
    int* __restrict__ cursor, int2* __restrict__ csr_sw,
    int n_edges, int n_nodes)
{
    __shared__ int s_cnt;
    __shared__ int s_d[EPB];
    __shared__ int s_e[EPB];
    int r = blockIdx.x & (RB - 1);
    int chunk = blockIdx.x >> 3;
    int lo = (int)((long long)r * n_nodes / RB);
    int hi = (int)((long long)(r + 1) * n_nodes / RB);
    if (threadIdx.x == 0) s_cnt = 0;
    __syncthreads();

    int base = chunk * EPB + threadIdx.x * EPT;
    int d[EPT];
    if (base + EPT - 1 < n_edges) {
        int4 v0 = *(const int4*)(edge_dst + base);
        int4 v1 = *(const int4*)(edge_dst + base + 4);
        d[0]=v0.x; d[1]=v0.y; d[2]=v0.z; d[3]=v0.w;
        d[4]=v1.x; d[5]=v1.y; d[6]=v1.z; d[7]=v1.w;
    } else {
        #pragma unroll
        for (int k = 0; k < EPT; ++k)
            d[k] = (base + k < n_edges) ? edge_dst[base + k] : -1;
    }

    int lane = threadIdx.x & 63;
    unsigned long long lt = (lane == 63) ? ~0ull >> 1
                                         : ((1ull << (lane + 1)) - 1) >> 1;
    #pragma unroll
    for (int k = 0; k < EPT; ++k) {
        bool m = (d[k] >= lo && d[k] < hi);
        unsigned long long bal = __ballot(m);
        int cw = __popcll(bal);
        if (cw) {
            int bs = 0;
            if (lane == 0) bs = atomicAdd(&s_cnt, cw);
            bs = __builtin_amdgcn_readfirstlane(bs);
            if (m) {
                int p = bs + __popcll(bal & lt);
                s_d[p] = d[k];
                s_e[p] = base + k;
            }
        }
    }
    __syncthreads();
    int c = s_cnt;
    for (int i = threadIdx.x; i < c; i += 256) {
        int dk = s_d[i];
        int e  = s_e[i];
        int pos = atomicAdd(&cursor[dk], 1);
        csr_sw[pos] = make_int2(edge_src[e], __float_as_int(edge_weight[e]));
    }
}

// ---------------------------------------------------------------------------
// Phase 2: wave-per-node gather, 8-deep ILP. csr reads wave-uniform;
// feature rows 256B-coalesced.
// ---------------------------------------------------------------------------
__global__ __launch_bounds__(256) void gather_kernel(
    const float* __restrict__ features, const int2* __restrict__ csr_sw,
    const int* __restrict__ offsets, float* __restrict__ neighbor, int n_nodes)
{
    int lane = threadIdx.x & 63;
    int gw = (blockIdx.x * 256 + threadIdx.x) >> 6;
    int nw = (gridDim.x * 256) >> 6;
    for (int i = gw; i < n_nodes; i += nw) {
        int beg = __builtin_amdgcn_readfirstlane(offsets[i]);
        int end = __builtin_amdgcn_readfirstlane(offsets[i + 1]);
        float acc = 0.f;
        int j = beg;
        for (; j + 7 < end; j += 8) {
            int2 p[8];
            float a[8];
            #pragma unroll
            for (int q = 0; q < 8; ++q) p[q] = csr_sw[j + q];
            #pragma unroll
            for (int q = 0; q < 8; ++q)
                a[q] = features[(size_t)p[q].x * D + lane];
            #pragma unroll
            for (int q = 0; q < 8; ++q)
                acc = fmaf(__int_as_float(p[q].y), a[q], acc);
        }
        for (; j < end; ++j) {
            int2 p = csr_sw[j];
            acc = fmaf(__int_as_float(p.y), features[(size_t)p.x * D + lane], acc);
        }
        neighbor[(size_t)i * D + lane] = acc;
    }
}

// ---------------------------------------------------------------------------
// Phase 3: out = normalize([features | neighbor] @ W^T + b)
// Round-9 lesson: EVERY readlane-per-fma variant landed 45-60us regardless of
// where W lived -> the v_readlane->SGPR->fma hazard chain was the bottleneck.
// This version has ZERO readlane/shfl in the hot loop:
//  - W transposed in LDS (Wt4[k4][o], float4; stride-16B read = optimal 8clk)
//  - each wave stages its 8 node-rows in wave-private LDS (no barrier), then
//    broadcasts comb[t][4k4..] via same-address ds_read_b128 (HW broadcast,
//    conflict-free), 4 fma per broadcast, 8 nodes per w4 read.
//  - persistent blocks: W staged once per block, grid-stride over groups.
// Floor: DS-pipe ~13-16us (1.6M broadcasts x ~4clk / 256 CU); VALU ~6us.
// ---------------------------------------------------------------------------
__global__ __launch_bounds__(256) void gemm_norm_kernel(
    const float* __restrict__ features, const float* __restrict__ neighbor,
    const float* __restrict__ W, const float* __restrict__ bias,
    float* __restrict__ out, int n_nodes)
{
    __shared__ float4 Wt4[32][64];      // 32 KB: Wt4[k4][o] = W[o][4k4..4k4+3]
    __shared__ float comb[4][8][128];   // 16 KB: per-wave staged node rows
    int tid = threadIdx.x;
    for (int idx = tid; idx < 32 * 64; idx += 256) {
        int k4 = idx >> 6, o = idx & 63;
        Wt4[k4][o] = *(const float4*)(W + (size_t)o * 128 + k4 * 4);
    }
    __syncthreads();

    int lane = tid & 63;
    int wv = tid >> 6;
    float bl = bias[lane];

    int ngroups = (n_nodes + 7) >> 3;
    for (int g = blockIdx.x * 4 + wv; g < ngroups; g += gridDim.x * 4) {
        int i0 = g * 8;
        int cnt = min(8, n_nodes - i0);

        // stage 8 node rows into wave-private LDS (no __syncthreads needed;
        // compiler orders the reads after writes via lgkmcnt on same object)
        #pragma unroll
        for (int t = 0; t < 8; ++t) {
            int i = i0 + ((t < cnt) ? t : 0);
            comb[wv][t][lane]      = features[(size_t)i * D + lane];
            comb[wv][t][64 + lane] = neighbor[(size_t)i * D + lane];
        }

        float acc[8];
        #pragma unroll
        for (int t = 0; t < 8; ++t) acc[t] = bl;

        #pragma unroll 4
        for (int k4 = 0; k4 < 32; ++k4) {
            float4 w4 = Wt4[k4][lane];
            #pragma unroll
            for (int t = 0; t < 8; ++t) {
                float4 c4 = *(const float4*)&comb[wv][t][4 * k4];
                acc[t] = fmaf(c4.x, w4.x, acc[t]);
                acc[t] = fmaf(c4.y, w4.y, acc[t]);
                acc[t] = fmaf(c4.z, w4.z, acc[t]);
                acc[t] = fmaf(c4.w, w4.w, acc[t]);
            }
        }

        #pragma unroll
        for (int t = 0; t < 8; ++t) {
            if (t < cnt) {
                float s = acc[t] * acc[t];
                #pragma unroll
                for (int m = 1; m < 64; m <<= 1) s += __shfl_xor(s, m, 64);
                out[(size_t)(i0 + t) * D + lane] =
                    acc[t] / fmaxf(sqrtf(s), 1e-12f);
            }
        }
    }
}

extern "C" void kernel_launch(void* const* d_in, const int* in_sizes, int n_in,
                              void* d_out, int out_size, void* d_ws, size_t ws_size,
                              hipStream_t stream) {
    const float* features    = (const float*)d_in[0];
    const int*   edge_src    = (const int*)d_in[1];
    const int*   edge_dst    = (const int*)d_in[2];
    const float* edge_weight = (const float*)d_in[3];
    const float* W           = (const float*)d_in[4];
    const float* b           = (const float*)d_in[5];
    float*       out         = (float*)d_out;

    int n = in_sizes[0] / D;
    int E = in_sizes[1];
    int nb = (n + TILE - 1) / TILE;
    int nchunks = (E + EPB - 1) / EPB;

    // workspace layout (256B-aligned slabs)
    char* ws = (char*)d_ws;
    auto al = [](size_t x) { return (x + 255) & ~(size_t)255; };
    size_t o = 0;
    int* deg      = (int*)(ws + o); o += al((size_t)n * 4);
    int* cursor   = (int*)(ws + o); o += al((size_t)n * 4);
    int* offsets  = (int*)(ws + o); o += al((size_t)(n + 1) * 4);
    int* partial  = (int*)(ws + o); o += al((size_t)nb * 4);
    int* ppref    = (int*)(ws + o); o += al((size_t)nb * 4);
    int2* csr_sw  = (int2*)(ws + o); o += al((size_t)E * 8);
    float* neighbor = (float*)(ws + o);

    hipMemsetAsync(deg, 0, (size_t)n * 4, stream);

    hist_kernel<<<nchunks * RB, 256, 0, stream>>>(edge_dst, deg, E, n);
    tile_sum_kernel<<<nb, 256, 0, stream>>>(deg, partial, n);
    scan_partial_kernel<<<1, 64, 0, stream>>>(partial, ppref, nb, offsets, n, E);
    scan_tile_kernel<<<nb, 256, 0, stream>>>(deg, ppref, offsets, cursor, n);
    fill_kernel<<<nchunks * RB, 256, 0, stream>>>(edge_src, edge_dst, edge_weight,
                                                  cursor, csr_sw, E, n);
    gather_kernel<<<2048, 256, 0, stream>>>(features, csr_sw, offsets,
                                            neighbor, n);
    gemm_norm_kernel<<<512, 256, 0, stream>>>(features, neighbor, W, b, out, n);
}

// Round 11
// 215.782 us; speedup vs baseline: 1.1152x; 1.0586x over previous
//
#include <hip/hip_runtime.h>

#define D 64
#define TILE 1024
#define RB 8               // dst ranges == XCD count
#define EPB 2048           // edges per chunk in hist/fill
#define EPT 8              // edges per thread (256 thr * 8 = 2048)

// ---------------------------------------------------------------------------
// Phase 1a: deg[dst]++ — range-partitioned + ballot-compaction.
// ---------------------------------------------------------------------------
__global__ __launch_bounds__(256) void hist_kernel(
    const int* __restrict__ edge_dst, int* __restrict__ deg,
    int n_edges, int n_nodes)
{
    __shared__ int s_cnt;
    __shared__ int s_d[EPB];
    int r = blockIdx.x & (RB - 1);
    int chunk = blockIdx.x >> 3;
    int lo = (int)((long long)r * n_nodes / RB);
    int hi = (int)((long long)(r + 1) * n_nodes / RB);
    if (threadIdx.x == 0) s_cnt = 0;
    __syncthreads();

    int base = chunk * EPB + threadIdx.x * EPT;
    int d[EPT];
    if (base + EPT - 1 < n_edges) {
        int4 v0 = *(const int4*)(edge_dst + base);
        int4 v1 = *(const int4*)(edge_dst + base + 4);
        d[0]=v0.x; d[1]=v0.y; d[2]=v0.z; d[3]=v0.w;
        d[4]=v1.x; d[5]=v1.y; d[6]=v1.z; d[7]=v1.w;
    } else {
        #pragma unroll
        for (int k = 0; k < EPT; ++k)
            d[k] = (base + k < n_edges) ? edge_dst[base + k] : -1;
    }

    int lane = threadIdx.x & 63;
    unsigned long long lt = (lane == 63) ? ~0ull >> 1
                                         : ((1ull << (lane + 1)) - 1) >> 1;
    #pragma unroll
    for (int k = 0; k < EPT; ++k) {
        bool m = (d[k] >= lo && d[k] < hi);
        unsigned long long bal = __ballot(m);
        int cw = __popcll(bal);
        if (cw) {
            int bs = 0;
            if (lane == 0) bs = atomicAdd(&s_cnt, cw);
            bs = __builtin_amdgcn_readfirstlane(bs);
            if (m) s_d[bs + __popcll(bal & lt)] = d[k];
        }
    }
    __syncthreads();
    int c = s_cnt;
    for (int i = threadIdx.x; i < c; i += 256) atomicAdd(&deg[s_d[i]], 1);
}

// ---------------------------------------------------------------------------
// Phase 1b-i: per-tile (1024 elems) sums. int4 loads, shfl reduce.
// ---------------------------------------------------------------------------
__global__ __launch_bounds__(256) void tile_sum_kernel(
    const int* __restrict__ deg, int* __restrict__ partial, int n)
{
    int t = threadIdx.x;
    int base = blockIdx.x * TILE + t * 4;
    int s = 0;
    if (base + 3 < n) {
        int4 v = *(const int4*)(deg + base);
        s = v.x + v.y + v.z + v.w;
    } else {
        for (int k = 0; k < 4; ++k) if (base + k < n) s += deg[base + k];
    }
    #pragma unroll
    for (int off = 1; off < 64; off <<= 1) s += __shfl_xor(s, off, 64);
    __shared__ int wsum[4];
    int lane = t & 63, wv = t >> 6;
    if (lane == 0) wsum[wv] = s;
    __syncthreads();
    if (t == 0) partial[blockIdx.x] = wsum[0] + wsum[1] + wsum[2] + wsum[3];
}

// ---------------------------------------------------------------------------
// Phase 1b-ii: exclusive scan of tile partials (1 block, 64 lanes).
// ---------------------------------------------------------------------------
__global__ __launch_bounds__(64) void scan_partial_kernel(
    const int* __restrict__ partial, int* __restrict__ ppref, int nb,
    int* __restrict__ offsets, int n, int n_edges)
{
    int lane = threadIdx.x;
    int carry = 0;
    for (int base = 0; base < nb; base += 64) {
        int idx = base + lane;
        int v = (idx < nb) ? partial[idx] : 0;
        int inc = v;
        #pragma unroll
        for (int off = 1; off < 64; off <<= 1) {
            int u = __shfl_up(inc, off, 64);
            if (lane >= off) inc += u;
        }
        if (idx < nb) ppref[idx] = carry + inc - v;
        carry += __shfl(inc, 63, 64);
    }
    if (lane == 0) offsets[n] = n_edges;
}

// ---------------------------------------------------------------------------
// Phase 1b-iii: per-tile scan -> offsets + cursor.
// ---------------------------------------------------------------------------
__global__ __launch_bounds__(256) void scan_tile_kernel(
    const int* __restrict__ deg, const int* __restrict__ ppref,
    int* __restrict__ offsets, int* __restrict__ cursor, int n)
{
    int t = threadIdx.x;
    int base = blockIdx.x * TILE + t * 4;
    int e0 = 0, e1 = 0, e2 = 0, e3 = 0;
    if (base + 3 < n) {
        int4 v = *(const int4*)(deg + base);
        e0 = v.x; e1 = v.y; e2 = v.z; e3 = v.w;
    } else {
        if (base + 0 < n) e0 = deg[base + 0];
        if (base + 1 < n) e1 = deg[base + 1];
        if (base + 2 < n) e2 = deg[base + 2];
        if (base + 3 < n) e3 = deg[base + 3];
    }
    int s = e0 + e1 + e2 + e3;
    int inc = s;
    int lane = t & 63, wv = t >> 6;
    #pragma unroll
    for (int off = 1; off < 64; off <<= 1) {
        int u = __shfl_up(inc, off, 64);
        if (lane >= off) inc += u;
    }
    __shared__ int wsum[4];
    if (lane == 63) wsum[wv] = inc;
    __syncthreads();
    int wpre = 0;
    for (int wq = 0; wq < wv; ++wq) wpre += wsum[wq];
    int excl = ppref[blockIdx.x] + wpre + inc - s;
    int o0 = excl, o1 = o0 + e0, o2 = o1 + e1, o3 = o2 + e2;
    if (base + 0 < n) { offsets[base + 0] = o0; cursor[base + 0] = o0; }
    if (base + 1 < n) { offsets[base + 1] = o1; cursor[base + 1] = o1; }
    if (base + 2 < n) { offsets[base + 2] = o2; cursor[base + 2] = o2; }
    if (base + 3 < n) { offsets[base + 3] = o3; cursor[base + 3] = o3; }
}

// ---------------------------------------------------------------------------
// Phase 1c: CSR fill, range-partitioned + ballot-compaction.
// ---------------------------------------------------------------------------
__global__ __launch_bounds__(256) void fill_kernel(
    const int* __restrict__ edge_src, const int* __restrict__ edge_dst,
    const float* __restrict__ edge_weight,
    int* __restrict__ cursor, int2* __restrict__ csr_sw,
    int n_edges, int n_nodes)
{
    __shared__ int s_cnt;
    __shared__ int s_d[EPB];
    __shared__ int s_e[EPB];
    int r = blockIdx.x & (RB - 1);
    int chunk = blockIdx.x >> 3;
    int lo = (int)((long long)r * n_nodes / RB);
    int hi = (int)((long long)(r + 1) * n_nodes / RB);
    if (threadIdx.x == 0) s_cnt = 0;
    __syncthreads();

    int base = chunk * EPB + threadIdx.x * EPT;
    int d[EPT];
    if (base + EPT - 1 < n_edges) {
        int4 v0 = *(const int4*)(edge_dst + base);
        int4 v1 = *(const int4*)(edge_dst + base + 4);
        d[0]=v0.x; d[1]=v0.y; d[2]=v0.z; d[3]=v0.w;
        d[4]=v1.x; d[5]=v1.y; d[6]=v1.z; d[7]=v1.w;
    } else {
        #pragma unroll
        for (int k = 0; k < EPT; ++k)
            d[k] = (base + k < n_edges) ? edge_dst[base + k] : -1;
    }

    int lane = threadIdx.x & 63;
    unsigned long long lt = (lane == 63) ? ~0ull >> 1
                                         : ((1ull << (lane + 1)) - 1) >> 1;
    #pragma unroll
    for (int k = 0; k < EPT; ++k) {
        bool m = (d[k] >= lo && d[k] < hi);
        unsigned long long bal = __ballot(m);
        int cw = __popcll(bal);
        if (cw) {
            int bs = 0;
            if (lane == 0) bs = atomicAdd(&s_cnt, cw);
            bs = __builtin_amdgcn_readfirstlane(bs);
            if (m) {
                int p = bs + __popcll(bal & lt);
                s_d[p] = d[k];
                s_e[p] = base + k;
            }
        }
    }
    __syncthreads();
    int c = s_cnt;
    for (int i = threadIdx.x; i < c; i += 256) {
        int dk = s_d[i];
        int e  = s_e[i];
        int pos = atomicAdd(&cursor[dk], 1);
        csr_sw[pos] = make_int2(edge_src[e], __float_as_int(edge_weight[e]));
    }
}

// ---------------------------------------------------------------------------
// Phase 2: wave-per-node gather, 8-deep ILP.
// ---------------------------------------------------------------------------
__global__ __launch_bounds__(256) void gather_kernel(
    const float* __restrict__ features, const int2* __restrict__ csr_sw,
    const int* __restrict__ offsets, float* __restrict__ neighbor, int n_nodes)
{
    int lane = threadIdx.x & 63;
    int gw = (blockIdx.x * 256 + threadIdx.x) >> 6;
    int nw = (gridDim.x * 256) >> 6;
    for (int i = gw; i < n_nodes; i += nw) {
        int beg = __builtin_amdgcn_readfirstlane(offsets[i]);
        int end = __builtin_amdgcn_readfirstlane(offsets[i + 1]);
        float acc = 0.f;
        int j = beg;
        for (; j + 7 < end; j += 8) {
            int2 p[8];
            float a[8];
            #pragma unroll
            for (int q = 0; q < 8; ++q) p[q] = csr_sw[j + q];
            #pragma unroll
            for (int q = 0; q < 8; ++q)
                a[q] = features[(size_t)p[q].x * D + lane];
            #pragma unroll
            for (int q = 0; q < 8; ++q)
                acc = fmaf(__int_as_float(p[q].y), a[q], acc);
        }
        for (; j < end; ++j) {
            int2 p = csr_sw[j];
            acc = fmaf(__int_as_float(p.y), features[(size_t)p.x * D + lane], acc);
        }
        neighbor[(size_t)i * D + lane] = acc;
    }
}

// ---------------------------------------------------------------------------
// W transpose (once per launch): Wt[k][o] = W[o][k].  Tiny; avoids the
// 32-way transpose-write bank conflict inside every gemm block.
// ---------------------------------------------------------------------------
__global__ __launch_bounds__(128) void wtrans_kernel(
    const float* __restrict__ W, float* __restrict__ Wt)
{
    int idx = blockIdx.x * 128 + threadIdx.x;
    if (idx < 64 * 128) {
        int o = idx >> 7, k = idx & 127;
        Wt[k * 64 + o] = W[idx];
    }
}

// ---------------------------------------------------------------------------
// Phase 3: out = normalize([features | neighbor] @ W^T + b)
// Round-10 lesson: DS pipe = 1 instr/~12cyc per CU shared by 4 SIMDs; DS:VALU
// capacity ~1:24. All broadcast-per-operand schemes (readlane OR LDS
// broadcast) sit at ~3.6 fma/DS -> DS-pipe-bound ~35-48us, regardless of
// where W lives. Fix: register tiling. Thread = 8 nodes x 8 outputs (64 acc);
// per k4-step: 8 global b128 (A, L1-resident lines) + 8 ds_read_b128 (W)
// -> 256 fma / 8 DS = 32:1 (> the 24:1 balance). Wave = 64 nodes x 64 outs.
//  - Wt[k][o] staged via linear conflict-free copy (pre-transposed kernel)
//  - hot Wt reads: 8 distinct addrs, banks repeat at nt=4 -> 2-way = free
//  - stores: lane-addr = lane*32B -> fully coalesced
//  - norm: shfl_xor 1/2/4 within the 8-lane nt-group
// Floors: VALU 6.8us/wave, DS 3.8us/CU, HBM 6.1us -> expect 10-15us.
// ---------------------------------------------------------------------------
__global__ __launch_bounds__(64) void gemm_norm_kernel(
    const float* __restrict__ features, const float* __restrict__ neighbor,
    const float* __restrict__ Wt,   // [128][64] pre-transposed
    const float* __restrict__ bias,
    float* __restrict__ out, int n_nodes)
{
    __shared__ float Wl[128 * 64];   // 32 KB
    int tid = threadIdx.x;           // 0..63, single wave per block
    {
        const float4* src = (const float4*)Wt;
        float4* dst = (float4*)Wl;
        #pragma unroll
        for (int i = 0; i < 32; ++i) dst[tid + i * 64] = src[tid + i * 64];
    }
    __syncthreads();

    int nt = tid & 7;    // output group: o = nt*8 + j
    int mt = tid >> 3;   // node group:   node = i0 + mt + 8*t

    long long i0 = (long long)blockIdx.x * 64;

    int nclamp[8];
    #pragma unroll
    for (int t = 0; t < 8; ++t) {
        long long node = i0 + mt + 8 * t;
        nclamp[t] = (int)((node < n_nodes) ? node : (n_nodes - 1));
    }

    float acc[8][8];
    #pragma unroll
    for (int t = 0; t < 8; ++t)
        #pragma unroll
        for (int j = 0; j < 8; ++j) acc[t][j] = 0.f;

    #pragma unroll
    for (int h = 0; h < 2; ++h) {
        const float* __restrict__ A = (h == 0) ? features : neighbor;
        #pragma unroll 1
        for (int k4 = 0; k4 < 16; ++k4) {
            float4 a4[8];
            #pragma unroll
            for (int t = 0; t < 8; ++t)
                a4[t] = *(const float4*)(A + (size_t)nclamp[t] * D + k4 * 4);
            int kk = h * 64 + k4 * 4;
            float4 b0[4], b1[4];
            #pragma unroll
            for (int i = 0; i < 4; ++i) {
                const float* wrow = Wl + (kk + i) * 64 + nt * 8;
                b0[i] = *(const float4*)(wrow);
                b1[i] = *(const float4*)(wrow + 4);
            }
            #pragma unroll
            for (int t = 0; t < 8; ++t) {
                float av[4] = {a4[t].x, a4[t].y, a4[t].z, a4[t].w};
                #pragma unroll
                for (int i = 0; i < 4; ++i) {
                    acc[t][0] = fmaf(av[i], b0[i].x, acc[t][0]);
                    acc[t][1] = fmaf(av[i], b0[i].y, acc[t][1]);
                    acc[t][2] = fmaf(av[i], b0[i].z, acc[t][2]);
                    acc[t][3] = fmaf(av[i], b0[i].w, acc[t][3]);
                    acc[t][4] = fmaf(av[i], b1[i].x, acc[t][4]);
                    acc[t][5] = fmaf(av[i], b1[i].y, acc[t][5]);
                    acc[t][6] = fmaf(av[i], b1[i].z, acc[t][6]);
                    acc[t][7] = fmaf(av[i], b1[i].w, acc[t][7]);
                }
            }
        }
    }

    float bl[8];
    #pragma unroll
    for (int j = 0; j < 8; ++j) bl[j] = bias[nt * 8 + j];

    #pragma unroll
    for (int t = 0; t < 8; ++t) {
        long long node = i0 + mt + 8 * t;
        float s = 0.f;
        #pragma unroll
        for (int j = 0; j < 8; ++j) {
            acc[t][j] += bl[j];
            s = fmaf(acc[t][j], acc[t][j], s);
        }
        s += __shfl_xor(s, 1, 64);
        s += __shfl_xor(s, 2, 64);
        s += __shfl_xor(s, 4, 64);
        float inv = 1.f / fmaxf(sqrtf(s), 1e-12f);
        if (node < n_nodes) {
            float4 o0 = make_float4(acc[t][0] * inv, acc[t][1] * inv,
                                    acc[t][2] * inv, acc[t][3] * inv);
            float4 o1 = make_float4(acc[t][4] * inv, acc[t][5] * inv,
                                    acc[t][6] * inv, acc[t][7] * inv);
            float* op = out + (size_t)node * D + nt * 8;
            *(float4*)op = o0;
            *(float4*)(op + 4) = o1;
        }
    }
}

extern "C" void kernel_launch(void* const* d_in, const int* in_sizes, int n_in,
                              void* d_out, int out_size, void* d_ws, size_t ws_size,
                              hipStream_t stream) {
    const float* features    = (const float*)d_in[0];
    const int*   edge_src    = (const int*)d_in[1];
    const int*   edge_dst    = (const int*)d_in[2];
    const float* edge_weight = (const float*)d_in[3];
    const float* W           = (const float*)d_in[4];
    const float* b           = (const float*)d_in[5];
    float*       out         = (float*)d_out;

    int n = in_sizes[0] / D;
    int E = in_sizes[1];
    int nb = (n + TILE - 1) / TILE;
    int nchunks = (E + EPB - 1) / EPB;

    // workspace layout (256B-aligned slabs)
    char* ws = (char*)d_ws;
    auto al = [](size_t x) { return (x + 255) & ~(size_t)255; };
    size_t o = 0;
    int* deg      = (int*)(ws + o); o += al((size_t)n * 4);
    int* cursor   = (int*)(ws + o); o += al((size_t)n * 4);
    int* offsets  = (int*)(ws + o); o += al((size_t)(n + 1) * 4);
    int* partial  = (int*)(ws + o); o += al((size_t)nb * 4);
    int* ppref    = (int*)(ws + o); o += al((size_t)nb * 4);
    float* Wt     = (float*)(ws + o); o += al((size_t)64 * 128 * 4);
    int2* csr_sw  = (int2*)(ws + o); o += al((size_t)E * 8);
    float* neighbor = (float*)(ws + o);

    hipMemsetAsync(deg, 0, (size_t)n * 4, stream);

    wtrans_kernel<<<64, 128, 0, stream>>>(W, Wt);
    hist_kernel<<<nchunks * RB, 256, 0, stream>>>(edge_dst, deg, E, n);
    tile_sum_kernel<<<nb, 256, 0, stream>>>(deg, partial, n);
    scan_partial_kernel<<<1, 64, 0, stream>>>(partial, ppref, nb, offsets, n, E);
    scan_tile_kernel<<<nb, 256, 0, stream>>>(deg, ppref, offsets, cursor, n);
    fill_kernel<<<nchunks * RB, 256, 0, stream>>>(edge_src, edge_dst, edge_weight,
                                                  cursor, csr_sw, E, n);
    gather_kernel<<<2048, 256, 0, stream>>>(features, csr_sw, offsets,
                                            neighbor, n);
    int gblocks = (n + 63) / 64;
    gemm_norm_kernel<<<gblocks, 64, 0, stream>>>(features, neighbor, Wt, b,
                                                 out, n);
}

// Round 15
// 186.109 us; speedup vs baseline: 1.2930x; 1.1594x over previous
//
#include <hip/hip_runtime.h>

#define D 64
#define TILE 1024
#define RB 8               // dst ranges == XCD count
#define EPB 2048           // edges per chunk in hist/fill
#define EPT 8              // edges per thread (256 thr * 8 = 2048)

// ---------------------------------------------------------------------------
// Phase 1a: deg[dst]++ — range-partitioned + ballot-compaction.
// Atomic returns the per-node slot; stored to slot[e] (u16) so fill
// needs no cursor atomic at all.
// ---------------------------------------------------------------------------
__global__ __launch_bounds__(256) void hist_kernel(
    const int* __restrict__ edge_dst, int* __restrict__ deg,
    unsigned short* __restrict__ slot, int n_edges, int n_nodes)
{
    __shared__ int s_cnt;
    __shared__ int s_d[EPB];
    __shared__ int s_e[EPB];
    int r = blockIdx.x & (RB - 1);
    int chunk = blockIdx.x >> 3;
    int lo = (int)((long long)r * n_nodes / RB);
    int hi = (int)((long long)(r + 1) * n_nodes / RB);
    if (threadIdx.x == 0) s_cnt = 0;
    __syncthreads();

    int base = chunk * EPB + threadIdx.x * EPT;
    int d[EPT];
    if (base + EPT - 1 < n_edges) {
        int4 v0 = *(const int4*)(edge_dst + base);
        int4 v1 = *(const int4*)(edge_dst + base + 4);
        d[0]=v0.x; d[1]=v0.y; d[2]=v0.z; d[3]=v0.w;
        d[4]=v1.x; d[5]=v1.y; d[6]=v1.z; d[7]=v1.w;
    } else {
        #pragma unroll
        for (int k = 0; k < EPT; ++k)
            d[k] = (base + k < n_edges) ? edge_dst[base + k] : -1;
    }

    int lane = threadIdx.x & 63;
    unsigned long long lt = (lane == 63) ? ~0ull >> 1
                                         : ((1ull << (lane + 1)) - 1) >> 1;
    #pragma unroll
    for (int k = 0; k < EPT; ++k) {
        bool m = (d[k] >= lo && d[k] < hi);
        unsigned long long bal = __ballot(m);
        int cw = __popcll(bal);
        if (cw) {
            int bs = 0;
            if (lane == 0) bs = atomicAdd(&s_cnt, cw);
            bs = __builtin_amdgcn_readfirstlane(bs);
            if (m) {
                int p = bs + __popcll(bal & lt);
                s_d[p] = d[k];
                s_e[p] = base + k;
            }
        }
    }
    __syncthreads();
    int c = s_cnt;
    for (int i = threadIdx.x; i < c; i += 256) {
        int old = atomicAdd(&deg[s_d[i]], 1);
        slot[s_e[i]] = (unsigned short)old;
    }
}

// ---------------------------------------------------------------------------
// Phase 1b-i: per-tile (1024 elems) sums. int4 loads, shfl reduce.
// ---------------------------------------------------------------------------
__global__ __launch_bounds__(256) void tile_sum_kernel(
    const int* __restrict__ deg, int* __restrict__ partial, int n)
{
    int t = threadIdx.x;
    int base = blockIdx.x * TILE + t * 4;
    int s = 0;
    if (base + 3 < n) {
        int4 v = *(const int4*)(deg + base);
        s = v.x + v.y + v.z + v.w;
    } else {
        for (int k = 0; k < 4; ++k) if (base + k < n) s += deg[base + k];
    }
    #pragma unroll
    for (int off = 1; off < 64; off <<= 1) s += __shfl_xor(s, off, 64);
    __shared__ int wsum[4];
    int lane = t & 63, wv = t >> 6;
    if (lane == 0) wsum[wv] = s;
    __syncthreads();
    if (t == 0) partial[blockIdx.x] = wsum[0] + wsum[1] + wsum[2] + wsum[3];
}

// ---------------------------------------------------------------------------
// Phase 1b-ii: per-tile scan -> offsets. Each wave redundantly reduces the
// (<=49) tile partials below blockIdx itself — scan_partial kernel removed.
// ---------------------------------------------------------------------------
__global__ __launch_bounds__(256) void scan_tile_kernel(
    const int* __restrict__ deg, const int* __restrict__ partial,
    int* __restrict__ offsets, int n, int n_edges)
{
    int t = threadIdx.x;
    int lane = t & 63, wv = t >> 6;

    // block prefix over earlier tiles (each wave computes it redundantly)
    int bp = 0;
    for (int j = lane; j < blockIdx.x; j += 64) bp += partial[j];
    #pragma unroll
    for (int off = 1; off < 64; off <<= 1) bp += __shfl_xor(bp, off, 64);

    int base = blockIdx.x * TILE + t * 4;
    int e0 = 0, e1 = 0, e2 = 0, e3 = 0;
    if (base + 3 < n) {
        int4 v = *(const int4*)(deg + base);
        e0 = v.x; e1 = v.y; e2 = v.z; e3 = v.w;
    } else {
        if (base + 0 < n) e0 = deg[base + 0];
        if (base + 1 < n) e1 = deg[base + 1];
        if (base + 2 < n) e2 = deg[base + 2];
        if (base + 3 < n) e3 = deg[base + 3];
    }
    int s = e0 + e1 + e2 + e3;
    int inc = s;
    #pragma unroll
    for (int off = 1; off < 64; off <<= 1) {
        int u = __shfl_up(inc, off, 64);
        if (lane >= off) inc += u;
    }
    __shared__ int wsum[4];
    if (lane == 63) wsum[wv] = inc;
    __syncthreads();
    int wpre = 0;
    for (int wq = 0; wq < wv; ++wq) wpre += wsum[wq];
    int excl = bp + wpre + inc - s;
    int o0 = excl, o1 = o0 + e0, o2 = o1 + e1, o3 = o2 + e2;
    if (base + 0 < n) offsets[base + 0] = o0;
    if (base + 1 < n) offsets[base + 1] = o1;
    if (base + 2 < n) offsets[base + 2] = o2;
    if (base + 3 < n) offsets[base + 3] = o3;
    if (blockIdx.x == 0 && t == 0) offsets[n] = n_edges;
}

// ---------------------------------------------------------------------------
// Phase 1c: CSR fill — NO atomics (pos = offsets[dst] + slot[e]).
// Range-partitioned + ballot-compaction for write locality + full-lane work.
// ---------------------------------------------------------------------------
__global__ __launch_bounds__(256) void fill_kernel(
    const int* __restrict__ edge_src, const int* __restrict__ edge_dst,
    const float* __restrict__ edge_weight,
    const unsigned short* __restrict__ slot,
    const int* __restrict__ offsets, int2* __restrict__ csr_sw,
    int n_edges, int n_nodes)
{
    __shared__ int s_cnt;
    __shared__ int s_d[EPB];
    __shared__ int s_e[EPB];
    int r = blockIdx.x & (RB - 1);
    int chunk = blockIdx.x >> 3;
    int lo = (int)((long long)r * n_nodes / RB);
    int hi = (int)((long long)(r + 1) * n_nodes / RB);
    if (threadIdx.x == 0) s_cnt = 0;
    __syncthreads();

    int base = chunk * EPB + threadIdx.x * EPT;
    int d[EPT];
    if (base + EPT - 1 < n_edges) {
        int4 v0 = *(const int4*)(edge_dst + base);
        int4 v1 = *(const int4*)(edge_dst + base + 4);
        d[0]=v0.x; d[1]=v0.y; d[2]=v0.z; d[3]=v0.w;
        d[4]=v1.x; d[5]=v1.y; d[6]=v1.z; d[7]=v1.w;
    } else {
        #pragma unroll
        for (int k = 0; k < EPT; ++k)
            d[k] = (base + k < n_edges) ? edge_dst[base + k] : -1;
    }

    int lane = threadIdx.x & 63;
    unsigned long long lt = (lane == 63) ? ~0ull >> 1
                                         : ((1ull << (lane + 1)) - 1) >> 1;
    #pragma unroll
    for (int k = 0; k < EPT; ++k) {
        bool m = (d[k] >= lo && d[k] < hi);
        unsigned long long bal = __ballot(m);
        int cw = __popcll(bal);
        if (cw) {
            int bs = 0;
            if (lane == 0) bs = atomicAdd(&s_cnt, cw);
            bs = __builtin_amdgcn_readfirstlane(bs);
            if (m) {
                int p = bs + __popcll(bal & lt);
                s_d[p] = d[k];
                s_e[p] = base + k;
            }
        }
    }
    __syncthreads();
    int c = s_cnt;
    for (int i = threadIdx.x; i < c; i += 256) {
        int dk = s_d[i];
        int e  = s_e[i];
        int pos = offsets[dk] + (int)slot[e];
        csr_sw[pos] = make_int2(edge_src[e], __float_as_int(edge_weight[e]));
    }
}

// ---------------------------------------------------------------------------
// Phase 2: wave-per-node gather, 8-deep ILP.
// ---------------------------------------------------------------------------
__global__ __launch_bounds__(256) void gather_kernel(
    const float* __restrict__ features, const int2* __restrict__ csr_sw,
    const int* __restrict__ offsets, float* __restrict__ neighbor, int n_nodes)
{
    int lane = threadIdx.x & 63;
    int gw = (blockIdx.x * 256 + threadIdx.x) >> 6;
    int nw = (gridDim.x * 256) >> 6;
    for (int i = gw; i < n_nodes; i += nw) {
        int beg = __builtin_amdgcn_readfirstlane(offsets[i]);
        int end = __builtin_amdgcn_readfirstlane(offsets[i + 1]);
        float acc = 0.f;
        int j = beg;
        for (; j + 7 < end; j += 8) {
            int2 p[8];
            float a[8];
            #pragma unroll
            for (int q = 0; q < 8; ++q) p[q] = csr_sw[j + q];
            #pragma unroll
            for (int q = 0; q < 8; ++q)
                a[q] = features[(size_t)p[q].x * D + lane];
            #pragma unroll
            for (int q = 0; q < 8; ++q)
                acc = fmaf(__int_as_float(p[q].y), a[q], acc);
        }
        for (; j < end; ++j) {
            int2 p = csr_sw[j];
            acc = fmaf(__int_as_float(p.y), features[(size_t)p.x * D + lane], acc);
        }
        neighbor[(size_t)i * D + lane] = acc;
    }
}

// ---------------------------------------------------------------------------
// W transpose (once per launch): Wt[k][o] = W[o][k].
// ---------------------------------------------------------------------------
__global__ __launch_bounds__(128) void wtrans_kernel(
    const float* __restrict__ W, float* __restrict__ Wt)
{
    int idx = blockIdx.x * 128 + threadIdx.x;
    if (idx < 64 * 128) {
        int o = idx >> 7, k = idx & 127;
        Wt[k * 64 + o] = W[idx];
    }
}

// ---------------------------------------------------------------------------
// Phase 3: out = normalize([features | neighbor] @ W^T + b)
// 256-thr blocks (4 waves, W staged once), MT=4 nodes/thread:
// 391 blocks = 1564 waves (~1.5/SIMD). Per k4-step: 4 global b128 + 8 DS
// b128 -> 128 fma : 8 DS = 16:1 (DS fine); acc 32 regs, ~100 VGPR total.
// ---------------------------------------------------------------------------
#define MT 4
__global__ __launch_bounds__(256) void gemm_norm_kernel(
    const float* __restrict__ features, const float* __restrict__ neighbor,
    const float* __restrict__ Wt,   // [128][64] pre-transposed
    const float* __restrict__ bias,
    float* __restrict__ out, int n_nodes)
{
    __shared__ float Wl[128 * 64];   // 32 KB
    int tid = threadIdx.x;
    {
        const float4* src = (const float4*)Wt;
        float4* dst = (float4*)Wl;
        #pragma unroll
        for (int i = 0; i < 8; ++i) dst[tid + i * 256] = src[tid + i * 256];
    }
    __syncthreads();

    int lane = tid & 63;
    int wv = tid >> 6;
    int nt = lane & 7;    // output group: o = nt*8 + j
    int mt = lane >> 3;   // node slot:    node = i0 + mt + 8*t

    long long i0 = (long long)blockIdx.x * (4 * 8 * MT) + wv * (8 * MT);

    int nclamp[MT];
    #pragma unroll
    for (int t = 0; t < MT; ++t) {
        long long node = i0 + mt + 8 * t;
        nclamp[t] = (int)((node < n_nodes) ? node : (n_nodes - 1));
    }

    float acc[MT][8];
    #pragma unroll
    for (int t = 0; t < MT; ++t)
        #pragma unroll
        for (int j = 0; j < 8; ++j) acc[t][j] = 0.f;

    #pragma unroll
    for (int h = 0; h < 2; ++h) {
        const float* __restrict__ A = (h == 0) ? features : neighbor;
        #pragma unroll 1
        for (int k4 = 0; k4 < 16; ++k4) {
            float4 a4[MT];
            #pragma unroll
            for (int t = 0; t < MT; ++t)
                a4[t] = *(const float4*)(A + (size_t)nclamp[t] * D + k4 * 4);
            int kk = h * 64 + k4 * 4;
            float4 b0[4], b1[4];
            #pragma unroll
            for (int i = 0; i < 4; ++i) {
                const float* wrow = Wl + (kk + i) * 64 + nt * 8;
                b0[i] = *(const float4*)(wrow);
                b1[i] = *(const float4*)(wrow + 4);
            }
            #pragma unroll
            for (int t = 0; t < MT; ++t) {
                float av[4] = {a4[t].x, a4[t].y, a4[t].z, a4[t].w};
                #pragma unroll
                for (int i = 0; i < 4; ++i) {
                    acc[t][0] = fmaf(av[i], b0[i].x, acc[t][0]);
                    acc[t][1] = fmaf(av[i], b0[i].y, acc[t][1]);
                    acc[t][2] = fmaf(av[i], b0[i].z, acc[t][2]);
                    acc[t][3] = fmaf(av[i], b0[i].w, acc[t][3]);
                    acc[t][4] = fmaf(av[i], b1[i].x, acc[t][4]);
                    acc[t][5] = fmaf(av[i], b1[i].y, acc[t][5]);
                    acc[t][6] = fmaf(av[i], b1[i].z, acc[t][6]);
                    acc[t][7] = fmaf(av[i], b1[i].w, acc[t][7]);
                }
            }
        }
    }

    float bl[8];
    #pragma unroll
    for (int j = 0; j < 8; ++j) bl[j] = bias[nt * 8 + j];

    #pragma unroll
    for (int t = 0; t < MT; ++t) {
        long long node = i0 + mt + 8 * t;
        float s = 0.f;
        #pragma unroll
        for (int j = 0; j < 8; ++j) {
            acc[t][j] += bl[j];
            s = fmaf(acc[t][j], acc[t][j], s);
        }
        s += __shfl_xor(s, 1, 64);
        s += __shfl_xor(s, 2, 64);
        s += __shfl_xor(s, 4, 64);
        float inv = 1.f / fmaxf(sqrtf(s), 1e-12f);
        if (node < n_nodes) {
            float4 o0 = make_float4(acc[t][0] * inv, acc[t][1] * inv,
                                    acc[t][2] * inv, acc[t][3] * inv);
            float4 o1 = make_float4(acc[t][4] * inv, acc[t][5] * inv,
                                    acc[t][6] * inv, acc[t][7] * inv);
            float* op = out + (size_t)node * D + nt * 8;
            *(float4*)op = o0;
            *(float4*)(op + 4) = o1;
        }
    }
}

extern "C" void kernel_launch(void* const* d_in, const int* in_sizes, int n_in,
                              void* d_out, int out_size, void* d_ws, size_t ws_size,
                              hipStream_t stream) {
    const float* features    = (const float*)d_in[0];
    const int*   edge_src    = (const int*)d_in[1];
    const int*   edge_dst    = (const int*)d_in[2];
    const float* edge_weight = (const float*)d_in[3];
    const float* W           = (const float*)d_in[4];
    const float* b           = (const float*)d_in[5];
    float*       out         = (float*)d_out;

    int n = in_sizes[0] / D;
    int E = in_sizes[1];
    int nb = (n + TILE - 1) / TILE;
    int nchunks = (E + EPB - 1) / EPB;

    // workspace layout (256B-aligned slabs)
    char* ws = (char*)d_ws;
    auto al = [](size_t x) { return (x + 255) & ~(size_t)255; };
    size_t o = 0;
    int* deg      = (int*)(ws + o); o += al((size_t)n * 4);
    int* offsets  = (int*)(ws + o); o += al((size_t)(n + 1) * 4);
    int* partial  = (int*)(ws + o); o += al((size_t)nb * 4);
    unsigned short* slot = (unsigned short*)(ws + o); o += al((size_t)E * 2);
    float* Wt     = (float*)(ws + o); o += al((size_t)64 * 128 * 4);
    int2* csr_sw  = (int2*)(ws + o); o += al((size_t)E * 8);
    float* neighbor = (float*)(ws + o);

    hipMemsetAsync(deg, 0, (size_t)n * 4, stream);

    wtrans_kernel<<<64, 128, 0, stream>>>(W, Wt);
    hist_kernel<<<nchunks * RB, 256, 0, stream>>>(edge_dst, deg, slot, E, n);
    tile_sum_kernel<<<nb, 256, 0, stream>>>(deg, partial, n);
    scan_tile_kernel<<<nb, 256, 0, stream>>>(deg, partial, offsets, n, E);
    fill_kernel<<<nchunks * RB, 256, 0, stream>>>(edge_src, edge_dst, edge_weight,
                                                  slot, offsets, csr_sw, E, n);
    gather_kernel<<<2048, 256, 0, stream>>>(features, csr_sw, offsets,
                                            neighbor, n);
    int gblocks = (n + 4 * 8 * MT - 1) / (4 * 8 * MT);
    gemm_norm_kernel<<<gblocks, 256, 0, stream>>>(features, neighbor, Wt, b,
                                                  out, n);
}